// Round 1
// baseline (308.869 us; speedup 1.0000x reference)
//
#include <hip/hip_runtime.h>
#include <stdint.h>

// ---------------------------------------------------------------------------
// MHA forward, MI355X/gfx950. B=2 S=2048 D=1024 H=16 hd=64.
// Pipeline: cvt x -> bf16 | transpose W's -> bf16 [N][K] | QKV MFMA GEMM ->
// Q/K [bh][s][64] + V^T [bh][64][s] bf16 | flash attn -> scrambled vals bf16 |
// out GEMM -> f32.
// ---------------------------------------------------------------------------

#define LOG2E 1.44269504088896340736f

typedef __attribute__((ext_vector_type(4))) float f32x4;
typedef __attribute__((ext_vector_type(8))) short short8v;
typedef __attribute__((ext_vector_type(8))) __bf16 bf16x8;

__device__ __forceinline__ unsigned short f2bf(float f) {
  unsigned u = __builtin_bit_cast(unsigned, f);
  u += 0x7FFFu + ((u >> 16) & 1u);  // RNE
  return (unsigned short)(u >> 16);
}

__device__ __forceinline__ unsigned pack2(float lo, float hi) {
  return (unsigned)f2bf(lo) | ((unsigned)f2bf(hi) << 16);
}

__device__ __forceinline__ f32x4 mfma16(short8v a, short8v b, f32x4 c) {
  return __builtin_amdgcn_mfma_f32_16x16x32_bf16(
      __builtin_bit_cast(bf16x8, a), __builtin_bit_cast(bf16x8, b), c, 0, 0, 0);
}

// async global->LDS, 16 bytes per lane. LDS dest = wave-uniform base + lane*16.
__device__ __forceinline__ void gload_lds16(const void* g, void* l) {
  __builtin_amdgcn_global_load_lds(
      (const __attribute__((address_space(1))) void*)(uintptr_t)g,
      (__attribute__((address_space(3))) void*)(uintptr_t)l, 16, 0, 0);
}

// ---------------------------------------------------------------------------
__global__ void cvt_x_kernel(const float4* __restrict__ src,
                             uint2* __restrict__ dst, int n4) {
  int i = blockIdx.x * 256 + threadIdx.x;
  if (i < n4) {
    float4 v = src[i];
    dst[i] = make_uint2(pack2(v.x, v.y), pack2(v.z, v.w));
  }
}

// f32 [R][C] -> bf16 [C][R]
__global__ void transpose_cvt_kernel(const float* __restrict__ src,
                                     unsigned short* __restrict__ dst,
                                     int R, int C) {
  __shared__ unsigned short tile[64][65];
  int tc = threadIdx.x & 63;
  int tr = threadIdx.x >> 6;
  int c0 = blockIdx.x * 64;
  int r0 = blockIdx.y * 64;
#pragma unroll
  for (int i = 0; i < 16; ++i) {
    int r = tr * 16 + i;
    tile[r][tc] = f2bf(src[(size_t)(r0 + r) * C + c0 + tc]);
  }
  __syncthreads();
#pragma unroll
  for (int i = 0; i < 16; ++i) {
    int cc = tr * 16 + i;
    dst[(size_t)(c0 + cc) * R + r0 + tc] = tile[tc][cc];
  }
}

// ---------------------------------------------------------------------------
// QKV GEMM: [4096,1024]bf16 @ WT[3072,1024]bf16 + bias -> Q/K [bh][2048][64],
// V^T [bh][64][2048], all bf16. 128x128 tile, BK=64, 4 waves (2x2 of 64x64).
__global__ __launch_bounds__(256, 2)
void gemm_qkv_kernel(const unsigned short* __restrict__ xbf,
                     const unsigned short* __restrict__ WT,
                     const float* __restrict__ bias,
                     unsigned short* __restrict__ Qb,
                     unsigned short* __restrict__ Kb,
                     unsigned short* __restrict__ VbT) {
  const int K = 1024;
  __shared__ __align__(16) unsigned short As[128 * 64];
  __shared__ __align__(16) unsigned short Bs[128 * 64];
  int tid = threadIdx.x;
  int lane = tid & 63;
  int wid = tid >> 6;
  int m0 = blockIdx.y * 128;
  int n0 = blockIdx.x * 128;
  int wm = (wid >> 1) * 64;
  int wn = (wid & 1) * 64;
  f32x4 acc[4][4] = {};
  for (int k0 = 0; k0 < K; k0 += 64) {
#pragma unroll
    for (int it = 0; it < 4; ++it) {
      int G = it * 256 + tid;
      int r = G >> 3, g = G & 7;
      int sg = g ^ (r & 7);  // inverse-swizzled source, linear LDS dest
      gload_lds16(xbf + (size_t)(m0 + r) * K + k0 + sg * 8, &As[G * 8]);
      gload_lds16(WT + (size_t)(n0 + r) * K + k0 + sg * 8, &Bs[G * 8]);
    }
    __syncthreads();
#pragma unroll
    for (int ks = 0; ks < 2; ++ks) {
      short8v a[4], bf[4];
      int kg = ks * 4 + (lane >> 4);
#pragma unroll
      for (int i = 0; i < 4; ++i) {
        int ra = wm + i * 16 + (lane & 15);
        a[i] = *(const short8v*)&As[ra * 64 + ((kg ^ (ra & 7)) << 3)];
        int rb = wn + i * 16 + (lane & 15);
        bf[i] = *(const short8v*)&Bs[rb * 64 + ((kg ^ (rb & 7)) << 3)];
      }
#pragma unroll
      for (int i = 0; i < 4; ++i)
#pragma unroll
        for (int j = 0; j < 4; ++j)
          acc[i][j] = mfma16(a[i], bf[j], acc[i][j]);
    }
    __syncthreads();
  }
  // epilogue: n -> (h, t, d); t=0 Q, t=1 K, t=2 V(transposed)
#pragma unroll
  for (int i = 0; i < 4; ++i) {
#pragma unroll
    for (int j = 0; j < 4; ++j) {
      int n = n0 + wn + j * 16 + (lane & 15);
      float bv = bias[n];
      int h = n / 192;
      int rr = n - h * 192;
      int t = rr >> 6;
      int d = rr & 63;
#pragma unroll
      for (int rg = 0; rg < 4; ++rg) {
        int m = m0 + wm + i * 16 + ((lane >> 4) << 2) + rg;
        int b = m >> 11, s = m & 2047;
        unsigned short val = f2bf(acc[i][j][rg] + bv);
        int bh = b * 16 + h;
        if (t == 2) {
          VbT[((size_t)bh * 64 + d) * 2048 + s] = val;
        } else {
          unsigned short* dst = (t == 0) ? Qb : Kb;
          dst[((size_t)bh * 2048 + s) * 64 + d] = val;
        }
      }
    }
  }
}

// ---------------------------------------------------------------------------
// Flash attention. Block = (b,h,qtile of 64). 4 waves x 16 q-rows each.
// Writes vals in the reference's scrambled reshape layout, bf16.
__global__ __launch_bounds__(256, 2)
void attn_kernel(const unsigned short* __restrict__ Qb,
                 const unsigned short* __restrict__ Kb,
                 const unsigned short* __restrict__ VbT,
                 const float* __restrict__ mask,
                 unsigned short* __restrict__ vals) {
  __shared__ __align__(16) unsigned short Ks[64 * 64];
  __shared__ __align__(16) unsigned short Vs[64 * 64];
  __shared__ __align__(16) unsigned short Ps[4][16 * 64];
  int tid = threadIdx.x;
  int lane = tid & 63;
  int wid = tid >> 6;
  int h = blockIdx.x & 15;          // h innermost: mask tile L2 reuse
  int qt = (blockIdx.x >> 4) & 31;
  int b = blockIdx.x >> 9;
  int bh = b * 16 + h;
  size_t bh_off = (size_t)bh * 2048 * 64;
  int q0 = qt * 64 + wid * 16;

  const unsigned short* qptr =
      Qb + bh_off + (size_t)(q0 + (lane & 15)) * 64 + ((lane >> 4) << 3);
  short8v qa0 = *(const short8v*)qptr;
  short8v qa1 = *(const short8v*)(qptr + 32);

  f32x4 o[4] = {};
  float m_run[4], l_run[4];
#pragma unroll
  for (int r = 0; r < 4; ++r) { m_run[r] = -1e30f; l_run[r] = 0.f; }

  const float* mrow =
      mask + ((size_t)b * 2048 + q0 + ((lane >> 4) << 2)) * 2048 + (lane & 15);

  for (int kt = 0; kt < 32; ++kt) {
#pragma unroll
    for (int it = 0; it < 2; ++it) {
      int G = it * 256 + tid;
      int r = G >> 3, g = G & 7;
      int sg = g ^ (r & 7);
      gload_lds16(Kb + bh_off + (size_t)(kt * 64 + r) * 64 + sg * 8, &Ks[G * 8]);
      gload_lds16(VbT + bh_off + (size_t)r * 2048 + kt * 64 + sg * 8, &Vs[G * 8]);
    }
    __syncthreads();

    // QK^T -> sf[f]: rows q=(lane>>4)*4+reg, col k = f*16 + (lane&15)
    f32x4 sf[4] = {};
#pragma unroll
    for (int ks = 0; ks < 2; ++ks) {
      short8v qa = ks ? qa1 : qa0;
      int kg = ks * 4 + (lane >> 4);
#pragma unroll
      for (int f = 0; f < 4; ++f) {
        int row = f * 16 + (lane & 15);
        short8v kb = *(const short8v*)&Ks[row * 64 + ((kg ^ (row & 7)) << 3)];
        sf[f] = mfma16(qa, kb, sf[f]);
      }
    }

    // scale + mask + online softmax
    float sc[4][4], mt[4];
#pragma unroll
    for (int r = 0; r < 4; ++r) mt[r] = -1e30f;
    const float* mp = mrow + kt * 64;
#pragma unroll
    for (int f = 0; f < 4; ++f)
#pragma unroll
      for (int r = 0; r < 4; ++r) {
        float v = sf[f][r] * 0.125f + mp[(size_t)r * 2048 + f * 16];
        sc[f][r] = v;
        mt[r] = fmaxf(mt[r], v);
      }
#pragma unroll
    for (int xm = 1; xm < 16; xm <<= 1)
#pragma unroll
      for (int r = 0; r < 4; ++r) mt[r] = fmaxf(mt[r], __shfl_xor(mt[r], xm));

    float alpha[4], rs[4];
#pragma unroll
    for (int r = 0; r < 4; ++r) {
      float mn = fmaxf(m_run[r], mt[r]);
      alpha[r] = exp2f((m_run[r] - mn) * LOG2E);
      m_run[r] = mn;
      rs[r] = 0.f;
    }
    unsigned short pb[4][4];
#pragma unroll
    for (int f = 0; f < 4; ++f)
#pragma unroll
      for (int r = 0; r < 4; ++r) {
        float p = exp2f((sc[f][r] - m_run[r]) * LOG2E);
        rs[r] += p;
        pb[f][r] = f2bf(p);
      }
#pragma unroll
    for (int xm = 1; xm < 16; xm <<= 1)
#pragma unroll
      for (int r = 0; r < 4; ++r) rs[r] += __shfl_xor(rs[r], xm);
#pragma unroll
    for (int r = 0; r < 4; ++r) l_run[r] = l_run[r] * alpha[r] + rs[r];
#pragma unroll
    for (int f = 0; f < 4; ++f)
#pragma unroll
      for (int r = 0; r < 4; ++r) o[f][r] *= alpha[r];

    // transpose P through per-wave swizzled LDS (wave-private: no barrier)
#pragma unroll
    for (int f = 0; f < 4; ++f)
#pragma unroll
      for (int r = 0; r < 4; ++r) {
        int prow = ((lane >> 4) << 2) + r;
        int pcol = f * 16 + (lane & 15);
        Ps[wid][prow * 64 + (((pcol >> 3) ^ (prow & 7)) << 3) + (pcol & 7)] =
            pb[f][r];
      }
    // PV: o[f] rows q, col d = f*16 + (lane&15)
#pragma unroll
    for (int ks = 0; ks < 2; ++ks) {
      int arow = lane & 15;
      int kg = ks * 4 + (lane >> 4);
      short8v pa =
          *(const short8v*)&Ps[wid][arow * 64 + ((kg ^ (arow & 7)) << 3)];
#pragma unroll
      for (int f = 0; f < 4; ++f) {
        int vrow = f * 16 + (lane & 15);
        short8v vb = *(const short8v*)&Vs[vrow * 64 + ((kg ^ (vrow & 7)) << 3)];
        o[f] = mfma16(pa, vb, o[f]);
      }
    }
    __syncthreads();
  }

  // epilogue: scrambled reshape (b,h,s,d) -> (b, h*128 + s/16, (s%16)*64 + d)
#pragma unroll
  for (int f = 0; f < 4; ++f)
#pragma unroll
    for (int r = 0; r < 4; ++r) {
      int s = q0 + ((lane >> 4) << 2) + r;
      int d = f * 16 + (lane & 15);
      int s2 = h * 128 + (s >> 4);
      int c2 = ((s & 15) << 6) + d;
      vals[((size_t)b * 2048 + s2) * 1024 + c2] = f2bf(o[f][r] / l_run[r]);
    }
}

// ---------------------------------------------------------------------------
// Output GEMM: vals[4096,1024]bf16 @ WoT[1024,1024]bf16 + bo -> out f32
__global__ __launch_bounds__(256, 2)
void gemm_out_kernel(const unsigned short* __restrict__ vals,
                     const unsigned short* __restrict__ WoT,
                     const float* __restrict__ bo,
                     float* __restrict__ out) {
  const int K = 1024;
  __shared__ __align__(16) unsigned short As[128 * 64];
  __shared__ __align__(16) unsigned short Bs[128 * 64];
  int tid = threadIdx.x;
  int lane = tid & 63;
  int wid = tid >> 6;
  int m0 = blockIdx.y * 128;
  int n0 = blockIdx.x * 128;
  int wm = (wid >> 1) * 64;
  int wn = (wid & 1) * 64;
  f32x4 acc[4][4] = {};
  for (int k0 = 0; k0 < K; k0 += 64) {
#pragma unroll
    for (int it = 0; it < 4; ++it) {
      int G = it * 256 + tid;
      int r = G >> 3, g = G & 7;
      int sg = g ^ (r & 7);
      gload_lds16(vals + (size_t)(m0 + r) * K + k0 + sg * 8, &As[G * 8]);
      gload_lds16(WoT + (size_t)(n0 + r) * K + k0 + sg * 8, &Bs[G * 8]);
    }
    __syncthreads();
#pragma unroll
    for (int ks = 0; ks < 2; ++ks) {
      short8v a[4], bf[4];
      int kg = ks * 4 + (lane >> 4);
#pragma unroll
      for (int i = 0; i < 4; ++i) {
        int ra = wm + i * 16 + (lane & 15);
        a[i] = *(const short8v*)&As[ra * 64 + ((kg ^ (ra & 7)) << 3)];
        int rb = wn + i * 16 + (lane & 15);
        bf[i] = *(const short8v*)&Bs[rb * 64 + ((kg ^ (rb & 7)) << 3)];
      }
#pragma unroll
      for (int i = 0; i < 4; ++i)
#pragma unroll
        for (int j = 0; j < 4; ++j)
          acc[i][j] = mfma16(a[i], bf[j], acc[i][j]);
    }
    __syncthreads();
  }
#pragma unroll
  for (int i = 0; i < 4; ++i) {
#pragma unroll
    for (int j = 0; j < 4; ++j) {
      int n = n0 + wn + j * 16 + (lane & 15);
      float bv = bo[n];
#pragma unroll
      for (int rg = 0; rg < 4; ++rg) {
        int m = m0 + wm + i * 16 + ((lane >> 4) << 2) + rg;
        out[(size_t)m * 1024 + n] = acc[i][j][rg] + bv;
      }
    }
  }
}

// ---------------------------------------------------------------------------
extern "C" void kernel_launch(void* const* d_in, const int* in_sizes, int n_in,
                              void* d_out, int out_size, void* d_ws,
                              size_t ws_size, hipStream_t stream) {
  const float* x    = (const float*)d_in[0];
  const float* mask = (const float*)d_in[1];
  const float* Wqkv = (const float*)d_in[2];
  const float* bqkv = (const float*)d_in[3];
  const float* Wo   = (const float*)d_in[4];
  const float* bo   = (const float*)d_in[5];
  float* out = (float*)d_out;

  char* ws = (char*)d_ws;
  // layout (bytes): xbf 8M | WqkvT 6M | WoT 2M | Qb 8M | Kb 8M | VbT 8M
  // vals aliases xbf (x dead after gemm_qkv). Total 40 MB.
  unsigned short* xbf   = (unsigned short*)(ws);
  unsigned short* WqkvT = (unsigned short*)(ws + 8388608);
  unsigned short* WoT   = (unsigned short*)(ws + 14680064);
  unsigned short* Qb    = (unsigned short*)(ws + 16777216);
  unsigned short* Kb    = (unsigned short*)(ws + 25165824);
  unsigned short* VbT   = (unsigned short*)(ws + 33554432);
  unsigned short* vals  = xbf;  // reuse

  hipLaunchKernelGGL(cvt_x_kernel, dim3(4096), dim3(256), 0, stream,
                     (const float4*)x, (uint2*)xbf, 1048576);
  hipLaunchKernelGGL(transpose_cvt_kernel, dim3(48, 16), dim3(256), 0, stream,
                     Wqkv, WqkvT, 1024, 3072);
  hipLaunchKernelGGL(transpose_cvt_kernel, dim3(16, 16), dim3(256), 0, stream,
                     Wo, WoT, 1024, 1024);
  hipLaunchKernelGGL(gemm_qkv_kernel, dim3(24, 32), dim3(256), 0, stream,
                     xbf, WqkvT, bqkv, Qb, Kb, VbT);
  hipLaunchKernelGGL(attn_kernel, dim3(1024), dim3(256), 0, stream,
                     Qb, Kb, VbT, mask, vals);
  hipLaunchKernelGGL(gemm_out_kernel, dim3(8, 32), dim3(256), 0, stream,
                     vals, WoT, bo, out);
}